// Round 1
// baseline (518.796 us; speedup 1.0000x reference)
//
#include <hip/hip_runtime.h>

#define NPA   4096
#define DHD   256      // H*DOUT
#define NHEAD 4
#define EDG   131072
#define OS    4104     // offsets row stride (16B aligned)

// ---------------- ws layout (float indices) ----------------
#define TBL_SZ    ((size_t)NPA * DHD)           // 1048576
#define OFF_TBL   ((size_t)0)                   // 8 tables: 0 WhP,1 Sp2p,2 Sp2a,3 Whp2s,4 WhA,5 Sa2p,6 Sa2a,7 Wha2s
#define OFF_WHIN  (OFF_TBL + 8 * TBL_SZ)        // 256
#define OFF_SCD   (OFF_WHIN + 256)              // 8
#define OFF_SCORE (OFF_SCD + 8)                 // 10 * 4096*4
#define OFF_ATTN  (OFF_SCORE + 10 * (size_t)NPA * 4)   // 4 * E * 4
#define OFF_CNT   (OFF_ATTN + 4 * (size_t)EDG * 4)     // 4*4096 ints
#define OFF_OFFS  (OFF_CNT + 4 * (size_t)NPA)          // 4*OS ints
#define OFF_CUR   (OFF_OFFS + 4 * (size_t)OS)          // 4*4096 ints
#define OFF_PERM  (OFF_CUR + 4 * (size_t)NPA)          // 4*E ints
#define OFF_DEN   (OFF_PERM + 4 * (size_t)EDG)         // 2*4
#define OFF_NUM   (OFF_DEN + 8)                        // 2*256

struct GemmArgs { const float* W[4]; const float* B[4]; };
struct ScoreArgs { const float* att[10]; int tbl[10]; };
struct EdgeArgs { const int* src[4]; const int* dst[4]; };

__device__ __forceinline__ float lrelu(float x) { return x >= 0.0f ? x : 0.2f * x; }

// C[w][m, n] = A[m,:] . W_w[n,:] + b_w[n], A:[4096,256], W:[256,256]
__global__ __launch_bounds__(256) void gemm_multi(const float* __restrict__ A,
                                                  GemmArgs ga, float* __restrict__ Cbase) {
    __shared__ float As[16][68];
    __shared__ float Bs[16][68];
    int bm = blockIdx.x;            // 64 m-tiles
    int bn = blockIdx.y;            // 16 n-tiles = 4 weights x 4
    int w = bn >> 2;
    const float* Wp = ga.W[w];
    const float* Bp = ga.B[w];
    int n0 = (bn & 3) * 64;
    int m0 = bm * 64;
    int t = threadIdx.x;
    int tx = t & 15, ty = t >> 4;
    float acc[4][4] = {};
    for (int k0 = 0; k0 < 256; k0 += 16) {
        int m = t >> 2;
        int kq = (t & 3) * 4;
        float4 av = *(const float4*)&A[(size_t)(m0 + m) * 256 + k0 + kq];
        As[kq + 0][m] = av.x; As[kq + 1][m] = av.y; As[kq + 2][m] = av.z; As[kq + 3][m] = av.w;
        float4 bv = *(const float4*)&Wp[(size_t)(n0 + m) * 256 + k0 + kq];
        Bs[kq + 0][m] = bv.x; Bs[kq + 1][m] = bv.y; Bs[kq + 2][m] = bv.z; Bs[kq + 3][m] = bv.w;
        __syncthreads();
#pragma unroll
        for (int k = 0; k < 16; ++k) {
            float4 a = *(const float4*)&As[k][ty * 4];
            float4 b = *(const float4*)&Bs[k][tx * 4];
            float ar[4] = {a.x, a.y, a.z, a.w};
            float br[4] = {b.x, b.y, b.z, b.w};
#pragma unroll
            for (int i = 0; i < 4; ++i)
#pragma unroll
                for (int j = 0; j < 4; ++j) acc[i][j] += ar[i] * br[j];
        }
        __syncthreads();
    }
    float4 bias = *(const float4*)&Bp[n0 + tx * 4];
    float* C = Cbase + (size_t)w * TBL_SZ;
#pragma unroll
    for (int i = 0; i < 4; ++i) {
        float4 v = {acc[i][0] + bias.x, acc[i][1] + bias.y, acc[i][2] + bias.z, acc[i][3] + bias.w};
        *(float4*)&C[(size_t)(m0 + ty * 4 + i) * 256 + n0 + tx * 4] = v;
    }
}

// Whin[j] = feat_state . W_in[j,:] + b_in[j]; also per-head dst scores for p2s/a2s
__global__ __launch_bounds__(256) void whin_kernel(const float* __restrict__ fs,
        const float* __restrict__ Win, const float* __restrict__ bin,
        const float* __restrict__ attP, const float* __restrict__ attA,
        float* __restrict__ whin, float* __restrict__ scd) {
    __shared__ float sf[256];
    int t = threadIdx.x;
    sf[t] = fs[t];
    __syncthreads();
    float acc = bin[t];
    for (int k = 0; k < 256; k += 4) {
        float4 wv = *(const float4*)&Win[(size_t)t * 256 + k];
        acc += wv.x * sf[k] + wv.y * sf[k + 1] + wv.z * sf[k + 2] + wv.w * sf[k + 3];
    }
    whin[t] = acc;
    float v1 = acc * attP[t];
    float v2 = acc * attA[t];
    for (int d = 32; d >= 1; d >>= 1) { v1 += __shfl_xor(v1, d); v2 += __shfl_xor(v2, d); }
    if ((t & 63) == 0) { scd[t >> 6] = v1; scd[4 + (t >> 6)] = v2; }
}

// 10 score tables [4096,4]: per-node per-head dot(Wh_row_head, att_head)
__global__ __launch_bounds__(256) void score_kernel(const float* __restrict__ tblBase,
                                                    ScoreArgs sa, float* __restrict__ scoreBase) {
    int job = blockIdx.y;
    int wave = threadIdx.x >> 6, lane = threadIdx.x & 63;
    int node = blockIdx.x * 4 + wave;
    const float* wh = tblBase + (size_t)sa.tbl[job] * TBL_SZ + (size_t)node * 256;
    float4 w = *(const float4*)&wh[lane * 4];
    float4 a = *(const float4*)&sa.att[job][lane * 4];
    float p = w.x * a.x + w.y * a.y + w.z * a.z + w.w * a.w;
    p += __shfl_xor(p, 1); p += __shfl_xor(p, 2); p += __shfl_xor(p, 4); p += __shfl_xor(p, 8);
    if ((lane & 15) == 0)
        scoreBase[(size_t)job * NPA * 4 + (size_t)node * 4 + (lane >> 4)] = p;
}

// per-edge head-softmax attention + dst histogram
__global__ __launch_bounds__(256) void attn_kernel(EdgeArgs ea, const float* __restrict__ scoreBase,
                                                   float* __restrict__ attnBase, int* __restrict__ counts) {
    int idx = blockIdx.x * 256 + threadIdx.x;     // 0..524287
    int r = idx >> 17;
    int e = idx & (EDG - 1);
    int s = ea.src[r][e];
    int d = ea.dst[r][e];
    const float* as = scoreBase + (size_t)r * NPA * 4;
    const float* ad = scoreBase + (size_t)(4 + r) * NPA * 4;
    float4 av = *(const float4*)&as[(size_t)s * 4];
    float4 dv = *(const float4*)&ad[(size_t)d * 4];
    float x0 = lrelu(av.x + dv.x), x1 = lrelu(av.y + dv.y);
    float x2 = lrelu(av.z + dv.z), x3 = lrelu(av.w + dv.w);
    float m = fmaxf(fmaxf(x0, x1), fmaxf(x2, x3));
    float e0 = __expf(x0 - m), e1 = __expf(x1 - m), e2 = __expf(x2 - m), e3 = __expf(x3 - m);
    float inv = 1.0f / (e0 + e1 + e2 + e3);
    float4 o = {e0 * inv, e1 * inv, e2 * inv, e3 * inv};
    *(float4*)&attnBase[((size_t)r * EDG + e) * 4] = o;
    atomicAdd(&counts[r * NPA + d], 1);
}

// exclusive scan of counts -> offsets (+ cursor copy), one block per relation
__global__ __launch_bounds__(1024) void scan_kernel(const int* __restrict__ counts,
                                                    int* __restrict__ offs, int* __restrict__ cur) {
    int r = blockIdx.x;
    int t = threadIdx.x;
    const int* c = counts + (size_t)r * NPA;
    int4 v = *(const int4*)&c[t * 4];
    int lsum = v.x + v.y + v.z + v.w;
    __shared__ int s[1024];
    s[t] = lsum;
    __syncthreads();
    for (int d = 1; d < 1024; d <<= 1) {
        int add = (t >= d) ? s[t - d] : 0;
        __syncthreads();
        s[t] += add;
        __syncthreads();
    }
    int base = s[t] - lsum;
    int4 ov = {base, base + v.x, base + v.x + v.y, base + v.x + v.y + v.z};
    *(int4*)&offs[(size_t)r * OS + t * 4] = ov;
    *(int4*)&cur[(size_t)r * NPA + t * 4] = ov;
    if (t == 1023) offs[(size_t)r * OS + NPA] = s[1023];
}

__global__ __launch_bounds__(256) void scatter_kernel(EdgeArgs ea, int* __restrict__ cur,
                                                      int* __restrict__ perm) {
    int idx = blockIdx.x * 256 + threadIdx.x;
    int r = idx >> 17;
    int e = idx & (EDG - 1);
    int d = ea.dst[r][e];
    int pos = atomicAdd(&cur[r * NPA + d], 1);
    perm[(size_t)r * EDG + pos] = e;
}

// one wave per dst node: acc += attn[e][head] * Wh_src[src[e]] row; add into acc table
__global__ __launch_bounds__(64) void agg_kernel(const int* __restrict__ offs,
        const int* __restrict__ perm, const int* __restrict__ esrc,
        const float* __restrict__ attn, const float* __restrict__ whsrc,
        float* __restrict__ accTbl) {
    int dn = blockIdx.x;
    int lane = threadIdx.x;
    int head = lane >> 4;
    int beg = offs[dn], end = offs[dn + 1];
    float4 acc = {0, 0, 0, 0};
    for (int i = beg; i < end; ++i) {
        int e = perm[i];
        int s = esrc[e];
        float4 at = *(const float4*)&attn[(size_t)e * 4];
        float a = head == 0 ? at.x : head == 1 ? at.y : head == 2 ? at.z : at.w;
        float4 wv = *(const float4*)&whsrc[(size_t)s * 256 + lane * 4];
        acc.x += a * wv.x; acc.y += a * wv.y; acc.z += a * wv.z; acc.w += a * wv.w;
    }
    float4* dst = (float4*)&accTbl[(size_t)dn * 256 + lane * 4];
    float4 cv = *dst;
    cv.x += acc.x; cv.y += acc.y; cv.z += acc.z; cv.w += acc.w;
    *dst = cv;
}

// state relations p2s (r=0, tbl3) / a2s (r=1, tbl7): softmax over all 4096 nodes
__global__ __launch_bounds__(256) void state_kernel(const float* __restrict__ tblBase,
        const float* __restrict__ scoreBase, const float* __restrict__ scd,
        float* __restrict__ den, float* __restrict__ num) {
    int r = blockIdx.y;
    int blk = blockIdx.x;        // 0..15
    int t = threadIdx.x;
    int h = t >> 6;
    const float* wh = tblBase + (size_t)(r == 0 ? 3 : 7) * TBL_SZ;
    const float* as = scoreBase + (size_t)(8 + r) * NPA * 4;
    float dh = scd[r * 4 + h];
    float dsum = 0.0f, acc = 0.0f;
    for (int i = blk; i < NPA; i += 16) {
        float x = lrelu(as[(size_t)i * 4 + h] + dh);
        float w = __expf(x);
        dsum += w;
        acc += w * wh[(size_t)i * 256 + t];
    }
    atomicAdd(&num[r * 256 + t], acc);
    if ((t & 63) == 0) atomicAdd(&den[r * 4 + h], dsum);
}

__global__ __launch_bounds__(256) void state_final(const float* __restrict__ whin,
        const float* __restrict__ den, const float* __restrict__ num, float* __restrict__ out) {
    int t = threadIdx.x;
    int h = t >> 6;
    float v = whin[t] + num[t] / den[h] + num[256 + t] / den[4 + h];
    out[t] = v > 0.0f ? v : 0.0f;
}

__global__ __launch_bounds__(256) void relu_kernel(const float* __restrict__ tblBase,
                                                   float* __restrict__ out) {
    size_t i = (size_t)blockIdx.x * 256 + threadIdx.x;   // 0..2097151
    float v = (i < TBL_SZ) ? tblBase[i] : tblBase[4 * TBL_SZ + (i - TBL_SZ)];
    out[i] = v > 0.0f ? v : 0.0f;
}

extern "C" void kernel_launch(void* const* d_in, const int* in_sizes, int n_in,
                              void* d_out, int out_size, void* d_ws, size_t ws_size,
                              hipStream_t stream) {
    const float* feat_P = (const float*)d_in[0];
    const float* feat_A = (const float*)d_in[1];
    const float* feat_S = (const float*)d_in[2];
    auto F = [&](int i) { return (const float*)d_in[i]; };
    float* ws = (float*)d_ws;
    float* tbl = ws + OFF_TBL;

    hipMemsetAsync(ws + OFF_CNT, 0, 4 * NPA * sizeof(int), stream);
    hipMemsetAsync(ws + OFF_DEN, 0, (8 + 512) * sizeof(float), stream);

    GemmArgs gp = {{F(3), F(7), F(9), F(15)}, {F(4), F(8), F(10), F(16)}};
    GemmArgs ga = {{F(5), F(11), F(13), F(17)}, {F(6), F(12), F(14), F(18)}};
    gemm_multi<<<dim3(64, 16), 256, 0, stream>>>(feat_P, gp, tbl);
    gemm_multi<<<dim3(64, 16), 256, 0, stream>>>(feat_A, ga, tbl + 4 * TBL_SZ);

    whin_kernel<<<1, 256, 0, stream>>>(feat_S, F(19), F(20), F(30), F(32),
                                       ws + OFF_WHIN, ws + OFF_SCD);

    ScoreArgs sa = {{F(21), F(23), F(25), F(27), F(22), F(24), F(26), F(28), F(29), F(31)},
                    {1, 2, 5, 6, 0, 4, 0, 4, 3, 7}};
    score_kernel<<<dim3(1024, 10), 256, 0, stream>>>(tbl, sa, ws + OFF_SCORE);

    EdgeArgs ea = {{(const int*)d_in[33], (const int*)d_in[35], (const int*)d_in[37], (const int*)d_in[39]},
                   {(const int*)d_in[34], (const int*)d_in[36], (const int*)d_in[38], (const int*)d_in[40]}};
    attn_kernel<<<2048, 256, 0, stream>>>(ea, ws + OFF_SCORE, ws + OFF_ATTN, (int*)(ws + OFF_CNT));
    scan_kernel<<<4, 1024, 0, stream>>>((int*)(ws + OFF_CNT), (int*)(ws + OFF_OFFS), (int*)(ws + OFF_CUR));
    scatter_kernel<<<2048, 256, 0, stream>>>(ea, (int*)(ws + OFF_CUR), (int*)(ws + OFF_PERM));

    // r: 0 p2p (src tbl1 -> acc tbl0), 1 p2a (tbl2 -> tbl4), 2 a2p (tbl5 -> tbl0), 3 a2a (tbl6 -> tbl4)
    const int srcIdx[4] = {1, 2, 5, 6};
    const int accIdx[4] = {0, 4, 0, 4};
    for (int r = 0; r < 4; ++r) {
        agg_kernel<<<4096, 64, 0, stream>>>((const int*)(ws + OFF_OFFS) + (size_t)r * OS,
                                            (const int*)(ws + OFF_PERM) + (size_t)r * EDG,
                                            ea.src[r],
                                            ws + OFF_ATTN + (size_t)r * EDG * 4,
                                            tbl + (size_t)srcIdx[r] * TBL_SZ,
                                            tbl + (size_t)accIdx[r] * TBL_SZ);
    }

    state_kernel<<<dim3(16, 2), 256, 0, stream>>>(tbl, ws + OFF_SCORE, ws + OFF_SCD,
                                                  ws + OFF_DEN, ws + OFF_NUM);
    state_final<<<1, 256, 0, stream>>>(ws + OFF_WHIN, ws + OFF_DEN, ws + OFF_NUM,
                                       (float*)d_out + 2 * TBL_SZ);
    relu_kernel<<<8192, 256, 0, stream>>>(tbl, (float*)d_out);
}

// Round 2
// 357.927 us; speedup vs baseline: 1.4494x; 1.4494x over previous
//
#include <hip/hip_runtime.h>

#define NPA   4096
#define DHD   256
#define EDG   131072
#define OS    4104
#define TBL_SZ ((size_t)NPA * DHD)   // elements per table

// ---- ws layout (byte offsets) ----
#define B_AH    ((size_t)0)                       // feats f16: 2 * 1M * 2B = 4 MB
#define B_WH    (B_AH + 2 * TBL_SZ * 2)           // weights f16: 8 * 65536 * 2 = 1 MB
#define B_TBL   (B_WH + (size_t)8 * 65536 * 2)    // 8 Wh tables f16 = 16 MB
#define B_SCORE (B_TBL + 8 * TBL_SZ * 2)          // 10 * 4096*4 fp32 = 640 KB
#define B_CNT   (B_SCORE + (size_t)10 * NPA * 4 * 4)
#define B_OFFS  (B_CNT + (size_t)4 * NPA * 4)
#define B_CUR   (B_OFFS + (size_t)4 * OS * 4)
#define B_SSRC  (B_CUR + (size_t)4 * NPA * 4)     // dst-sorted src idx: 4*E*4 = 2 MB
#define B_SATT  (B_SSRC + (size_t)4 * EDG * 4)    // dst-sorted attn: 4*E*16 = 8 MB
#define B_WHIN  (B_SATT + (size_t)4 * EDG * 16)   // 256 fp32
#define B_SCD   (B_WHIN + 256 * 4)                // 8 fp32
#define B_DEN   (B_SCD + 8 * 4)                   // 8 fp32
#define B_NUM   (B_DEN + 8 * 4)                   // 512 fp32

typedef _Float16 half8 __attribute__((ext_vector_type(8)));
typedef _Float16 half4 __attribute__((ext_vector_type(4)));
typedef float floatx4 __attribute__((ext_vector_type(4)));

struct CastArgs { const float* src[10]; };
struct BiasArgs { const float* b[8]; };
struct ScoreArgs { const float* att[10]; int tbl[10]; };
struct EdgeArgs { const int* src[4]; const int* dst[4]; };

__device__ __forceinline__ float lrelu(float x) { return x >= 0.0f ? x : 0.2f * x; }

// fp32 -> f16 for 2 feature matrices (1M each) + 8 weight matrices (64K each)
__global__ __launch_bounds__(256) void cast_kernel(CastArgs ca, _Float16* __restrict__ dst) {
    size_t i4 = ((size_t)blockIdx.x * 256 + threadIdx.x) * 4;
    const float* s; size_t off;
    if (i4 < TBL_SZ)            { s = ca.src[0]; off = i4; }
    else if (i4 < 2 * TBL_SZ)   { s = ca.src[1]; off = i4 - TBL_SZ; }
    else { size_t r = i4 - 2 * TBL_SZ; s = ca.src[2 + (r >> 16)]; off = r & 65535; }
    float4 v = *(const float4*)(s + off);
    half4 h = {(_Float16)v.x, (_Float16)v.y, (_Float16)v.z, (_Float16)v.w};
    *(half4*)(dst + i4) = h;
}

// C[m,n] = A[m,:] . W[n,:] + b[n] via MFMA f16, 8 jobs (blockIdx.z)
// jobs 0-3: feat_P x {W_P, W_p2p, W_p2a, W_p2s}; 4-7: feat_A x {W_A, W_a2p, W_a2a, W_a2s}
__global__ __launch_bounds__(256) void gemm_mfma(const _Float16* __restrict__ Ah,
        const _Float16* __restrict__ Wh, BiasArgs ba, _Float16* __restrict__ tblBase) {
    int j = blockIdx.z;
    const _Float16* A = Ah + (size_t)(j >> 2) * TBL_SZ;
    const _Float16* W = Wh + (size_t)j * 65536;
    const float* bias = ba.b[j];
    _Float16* out = tblBase + (size_t)j * TBL_SZ;
    int wave = threadIdx.x >> 6, lane = threadIdx.x & 63;
    int quad = lane >> 4, l16 = lane & 15;
    int mr = blockIdx.x * 64 + (wave >> 1) * 32;
    int nc = blockIdx.y * 64 + (wave & 1) * 32;
    const _Float16* a0p = A + (size_t)(mr + l16) * 256 + quad * 8;
    const _Float16* a1p = a0p + 16 * 256;
    const _Float16* b0p = W + (size_t)(nc + l16) * 256 + quad * 8;
    const _Float16* b1p = b0p + 16 * 256;
    floatx4 acc00 = {0,0,0,0}, acc01 = {0,0,0,0}, acc10 = {0,0,0,0}, acc11 = {0,0,0,0};
#pragma unroll
    for (int k0 = 0; k0 < 256; k0 += 32) {
        half8 a0 = *(const half8*)(a0p + k0);
        half8 a1 = *(const half8*)(a1p + k0);
        half8 b0 = *(const half8*)(b0p + k0);
        half8 b1 = *(const half8*)(b1p + k0);
        acc00 = __builtin_amdgcn_mfma_f32_16x16x32_f16(a0, b0, acc00, 0, 0, 0);
        acc01 = __builtin_amdgcn_mfma_f32_16x16x32_f16(a0, b1, acc01, 0, 0, 0);
        acc10 = __builtin_amdgcn_mfma_f32_16x16x32_f16(a1, b0, acc10, 0, 0, 0);
        acc11 = __builtin_amdgcn_mfma_f32_16x16x32_f16(a1, b1, acc11, 0, 0, 0);
    }
    float bc0 = bias[nc + l16];
    float bc1 = bias[nc + 16 + l16];
#pragma unroll
    for (int i = 0; i < 4; ++i) {
        int r0 = mr + quad * 4 + i;
        out[(size_t)r0 * 256 + nc + l16]             = (_Float16)(acc00[i] + bc0);
        out[(size_t)r0 * 256 + nc + 16 + l16]        = (_Float16)(acc01[i] + bc1);
        out[(size_t)(r0 + 16) * 256 + nc + l16]      = (_Float16)(acc10[i] + bc0);
        out[(size_t)(r0 + 16) * 256 + nc + 16 + l16] = (_Float16)(acc11[i] + bc1);
    }
}

// Whin (1x256, fp32) + per-head dst scores for p2s/a2s
__global__ __launch_bounds__(256) void whin_kernel(const float* __restrict__ fs,
        const float* __restrict__ Win, const float* __restrict__ bin,
        const float* __restrict__ attP, const float* __restrict__ attA,
        float* __restrict__ whin, float* __restrict__ scd) {
    __shared__ float sf[256];
    int t = threadIdx.x;
    sf[t] = fs[t];
    __syncthreads();
    float acc = bin[t];
    for (int k = 0; k < 256; k += 4) {
        float4 wv = *(const float4*)&Win[(size_t)t * 256 + k];
        acc += wv.x * sf[k] + wv.y * sf[k + 1] + wv.z * sf[k + 2] + wv.w * sf[k + 3];
    }
    whin[t] = acc;
    float v1 = acc * attP[t];
    float v2 = acc * attA[t];
    for (int d = 32; d >= 1; d >>= 1) { v1 += __shfl_xor(v1, d); v2 += __shfl_xor(v2, d); }
    if ((t & 63) == 0) { scd[t >> 6] = v1; scd[4 + (t >> 6)] = v2; }
}

// 10 score tables [4096,4] from f16 Wh tables
__global__ __launch_bounds__(256) void score_kernel(const _Float16* __restrict__ tblBase,
                                                    ScoreArgs sa, float* __restrict__ scoreBase) {
    int job = blockIdx.y;
    int wave = threadIdx.x >> 6, lane = threadIdx.x & 63;
    int node = blockIdx.x * 4 + wave;
    const _Float16* wh = tblBase + (size_t)sa.tbl[job] * TBL_SZ + (size_t)node * 256 + lane * 4;
    half4 w = *(const half4*)wh;
    float4 a = *(const float4*)&sa.att[job][lane * 4];
    float p = (float)w[0] * a.x + (float)w[1] * a.y + (float)w[2] * a.z + (float)w[3] * a.w;
    p += __shfl_xor(p, 1); p += __shfl_xor(p, 2); p += __shfl_xor(p, 4); p += __shfl_xor(p, 8);
    if ((lane & 15) == 0)
        scoreBase[(size_t)job * NPA * 4 + (size_t)node * 4 + (lane >> 4)] = p;
}

__global__ __launch_bounds__(256) void count_kernel(EdgeArgs ea, int* __restrict__ counts) {
    int idx = blockIdx.x * 256 + threadIdx.x;
    int r = idx >> 17;
    int e = idx & (EDG - 1);
    atomicAdd(&counts[r * NPA + ea.dst[r][e]], 1);
}

__global__ __launch_bounds__(1024) void scan_kernel(const int* __restrict__ counts,
                                                    int* __restrict__ offs, int* __restrict__ cur) {
    int r = blockIdx.x;
    int t = threadIdx.x;
    const int* c = counts + (size_t)r * NPA;
    int4 v = *(const int4*)&c[t * 4];
    int lsum = v.x + v.y + v.z + v.w;
    __shared__ int s[1024];
    s[t] = lsum;
    __syncthreads();
    for (int d = 1; d < 1024; d <<= 1) {
        int add = (t >= d) ? s[t - d] : 0;
        __syncthreads();
        s[t] += add;
        __syncthreads();
    }
    int base = s[t] - lsum;
    int4 ov = {base, base + v.x, base + v.x + v.y, base + v.x + v.y + v.z};
    *(int4*)&offs[(size_t)r * OS + t * 4] = ov;
    *(int4*)&cur[(size_t)r * NPA + t * 4] = ov;
    if (t == 1023) offs[(size_t)r * OS + NPA] = s[1023];
}

// compute per-edge head-softmax attn and write it dst-sorted (+ sorted src idx)
__global__ __launch_bounds__(256) void scatter_attn(EdgeArgs ea, const float* __restrict__ scoreBase,
        int* __restrict__ cur, int* __restrict__ ssrc, float* __restrict__ satt) {
    int idx = blockIdx.x * 256 + threadIdx.x;
    int r = idx >> 17;
    int e = idx & (EDG - 1);
    int s = ea.src[r][e];
    int d = ea.dst[r][e];
    const float* as = scoreBase + (size_t)r * NPA * 4;
    const float* ad = scoreBase + (size_t)(4 + r) * NPA * 4;
    float4 av = *(const float4*)&as[(size_t)s * 4];
    float4 dv = *(const float4*)&ad[(size_t)d * 4];
    float x0 = lrelu(av.x + dv.x), x1 = lrelu(av.y + dv.y);
    float x2 = lrelu(av.z + dv.z), x3 = lrelu(av.w + dv.w);
    float m = fmaxf(fmaxf(x0, x1), fmaxf(x2, x3));
    float e0 = __expf(x0 - m), e1 = __expf(x1 - m), e2 = __expf(x2 - m), e3 = __expf(x3 - m);
    float inv = 1.0f / (e0 + e1 + e2 + e3);
    int pos = atomicAdd(&cur[r * NPA + d], 1);
    ssrc[(size_t)r * EDG + pos] = s;
    float4 o = {e0 * inv, e1 * inv, e2 * inv, e3 * inv};
    *(float4*)&satt[((size_t)r * EDG + pos) * 4] = o;
}

// per dst node: out = relu(Wh_skip + sum over 2 relations of attn*Wh_src). Writes d_out.
__global__ __launch_bounds__(256) void agg_kernel(const int* __restrict__ offs,
        const int* __restrict__ ssrc, const float* __restrict__ satt,
        const _Float16* __restrict__ tblBase, float* __restrict__ outBase) {
    int side = blockIdx.y;                      // 0 = P, 1 = A
    int wave = threadIdx.x >> 6, lane = threadIdx.x & 63;
    int dn = blockIdx.x * 4 + wave;
    int head = lane >> 4;
    const _Float16* skip = tblBase + (size_t)(side * 4) * TBL_SZ + (size_t)dn * 256 + lane * 4;
    half4 sv = *(const half4*)skip;
    float a0 = sv[0], a1 = sv[1], a2 = sv[2], a3 = sv[3];
    const int stbl[4] = {1, 2, 5, 6};
#pragma unroll
    for (int q = 0; q < 2; ++q) {
        int r = side + q * 2;
        const int* of = offs + (size_t)r * OS;
        const int* sp = ssrc + (size_t)r * EDG;
        const float* at = satt + (size_t)r * EDG * 4;
        const _Float16* wh = tblBase + (size_t)stbl[r] * TBL_SZ;
        int beg = of[dn], end = of[dn + 1];
        for (int i = beg; i < end; ++i) {
            int s = sp[i];
            float4 av = *(const float4*)&at[(size_t)i * 4];
            float a = head == 0 ? av.x : head == 1 ? av.y : head == 2 ? av.z : av.w;
            half4 wv = *(const half4*)&wh[(size_t)s * 256 + lane * 4];
            a0 += a * (float)wv[0]; a1 += a * (float)wv[1];
            a2 += a * (float)wv[2]; a3 += a * (float)wv[3];
        }
    }
    float4 o = {fmaxf(a0, 0.f), fmaxf(a1, 0.f), fmaxf(a2, 0.f), fmaxf(a3, 0.f)};
    *(float4*)&outBase[((size_t)side * NPA + dn) * 256 + lane * 4] = o;
}

// state relations p2s (tbl3) / a2s (tbl7): softmax over 4096 nodes
__global__ __launch_bounds__(256) void state_kernel(const _Float16* __restrict__ tblBase,
        const float* __restrict__ scoreBase, const float* __restrict__ scd,
        float* __restrict__ den, float* __restrict__ num) {
    int r = blockIdx.y;
    int blk = blockIdx.x;                       // 0..127
    int t = threadIdx.x;
    int h = t >> 6;
    const _Float16* wh = tblBase + (size_t)(r == 0 ? 3 : 7) * TBL_SZ;
    const float* as = scoreBase + (size_t)(8 + r) * NPA * 4;
    float dh = scd[r * 4 + h];
    float dsum = 0.0f, acc = 0.0f;
    for (int i = blk; i < NPA; i += 128) {
        float x = lrelu(as[(size_t)i * 4 + h] + dh);
        float w = __expf(x);
        dsum += w;
        acc += w * (float)wh[(size_t)i * 256 + t];
    }
    atomicAdd(&num[r * 256 + t], acc);
    if ((t & 63) == 0) atomicAdd(&den[r * 4 + h], dsum);
}

__global__ __launch_bounds__(256) void state_final(const float* __restrict__ whin,
        const float* __restrict__ den, const float* __restrict__ num, float* __restrict__ out) {
    int t = threadIdx.x;
    int h = t >> 6;
    float v = whin[t] + num[t] / den[h] + num[256 + t] / den[4 + h];
    out[t] = v > 0.0f ? v : 0.0f;
}

extern "C" void kernel_launch(void* const* d_in, const int* in_sizes, int n_in,
                              void* d_out, int out_size, void* d_ws, size_t ws_size,
                              hipStream_t stream) {
    auto F = [&](int i) { return (const float*)d_in[i]; };
    char* ws = (char*)d_ws;
    _Float16* Ah  = (_Float16*)(ws + B_AH);
    _Float16* Wh  = (_Float16*)(ws + B_WH);
    _Float16* tbl = (_Float16*)(ws + B_TBL);
    float* score  = (float*)(ws + B_SCORE);
    int* cnt      = (int*)(ws + B_CNT);
    int* offs     = (int*)(ws + B_OFFS);
    int* cur      = (int*)(ws + B_CUR);
    int* ssrc     = (int*)(ws + B_SSRC);
    float* satt   = (float*)(ws + B_SATT);
    float* whin   = (float*)(ws + B_WHIN);
    float* scd    = (float*)(ws + B_SCD);
    float* den    = (float*)(ws + B_DEN);
    float* num    = (float*)(ws + B_NUM);

    hipMemsetAsync(cnt, 0, 4 * NPA * sizeof(int), stream);
    hipMemsetAsync(den, 0, (8 + 512) * sizeof(float), stream);

    CastArgs ca = {{F(0), F(1), F(3), F(7), F(9), F(15), F(5), F(11), F(13), F(17)}};
    cast_kernel<<<2560, 256, 0, stream>>>(ca, Ah);

    BiasArgs ba = {{F(4), F(8), F(10), F(16), F(6), F(12), F(14), F(18)}};
    gemm_mfma<<<dim3(64, 4, 8), 256, 0, stream>>>(Ah, Wh, ba, tbl);

    whin_kernel<<<1, 256, 0, stream>>>(F(2), F(19), F(20), F(30), F(32), whin, scd);

    ScoreArgs sa = {{F(21), F(23), F(25), F(27), F(22), F(24), F(26), F(28), F(29), F(31)},
                    {1, 2, 5, 6, 0, 4, 0, 4, 3, 7}};
    score_kernel<<<dim3(1024, 10), 256, 0, stream>>>(tbl, sa, score);

    EdgeArgs ea = {{(const int*)d_in[33], (const int*)d_in[35], (const int*)d_in[37], (const int*)d_in[39]},
                   {(const int*)d_in[34], (const int*)d_in[36], (const int*)d_in[38], (const int*)d_in[40]}};
    count_kernel<<<2048, 256, 0, stream>>>(ea, cnt);
    scan_kernel<<<4, 1024, 0, stream>>>(cnt, offs, cur);
    scatter_attn<<<2048, 256, 0, stream>>>(ea, score, cur, ssrc, satt);

    agg_kernel<<<dim3(1024, 2), 256, 0, stream>>>(offs, ssrc, satt, tbl, (float*)d_out);

    state_kernel<<<dim3(128, 2), 256, 0, stream>>>(tbl, score, scd, den, num);
    state_final<<<1, 256, 0, stream>>>(whin, den, num, (float*)d_out + 2 * TBL_SZ);
}

// Round 3
// 304.646 us; speedup vs baseline: 1.7029x; 1.1749x over previous
//
#include <hip/hip_runtime.h>

#define NPA   4096
#define DHD   256
#define EDG   131072
#define OS    4104
#define TBL_SZ ((size_t)NPA * DHD)   // elements per table

// ---- ws layout (byte offsets) ----
#define B_AH    ((size_t)0)                       // feats f16: 2 * 1M * 2B = 4 MB
#define B_WH    (B_AH + 2 * TBL_SZ * 2)           // weights f16: 8 * 65536 * 2 = 1 MB
#define B_TBL   (B_WH + (size_t)8 * 65536 * 2)    // 8 Wh tables f16 = 16 MB
#define B_SCORE (B_TBL + 8 * TBL_SZ * 2)          // 10 * 4096*4 fp32 = 640 KB
#define B_CNT   (B_SCORE + (size_t)10 * NPA * 4 * 4)
#define B_OFFS  (B_CNT + (size_t)4 * NPA * 4)
#define B_CUR   (B_OFFS + (size_t)4 * OS * 4)
#define B_PKT   (B_CUR + (size_t)4 * NPA * 4)     // dst-sorted {src, attn f16x4}: 4*E*16 = 8 MB
#define B_WHIN  (B_PKT + (size_t)4 * EDG * 16)    // 256 fp32
#define B_SCD   (B_WHIN + 256 * 4)                // 8 fp32   (memset together with den/num)
#define B_DEN   (B_SCD + 8 * 4)                   // 8 fp32
#define B_NUM   (B_DEN + 8 * 4)                   // 512 fp32

typedef _Float16 half8 __attribute__((ext_vector_type(8)));
typedef _Float16 half4 __attribute__((ext_vector_type(4)));
typedef _Float16 half2v __attribute__((ext_vector_type(2)));
typedef float floatx4 __attribute__((ext_vector_type(4)));

struct CastArgs { const float* src[10]; };
struct BiasArgs { const float* b[8]; };
struct ScoreArgs { const float* att[10]; int tbl[10]; };
struct EdgeArgs { const int* src[4]; const int* dst[4]; };

__device__ __forceinline__ float lrelu(float x) { return x >= 0.0f ? x : 0.2f * x; }

__device__ __forceinline__ int pack2(float a, float b) {
    half2v h = {(_Float16)a, (_Float16)b};
    return __builtin_bit_cast(int, h);
}

__device__ __forceinline__ float asel(const int4& p, int head) {
    int bits = (head & 2) ? p.z : p.y;
    half2v x = __builtin_bit_cast(half2v, bits);
    return (float)((head & 1) ? x[1] : x[0]);
}

// fp32 -> f16 for 2 feature matrices (1M each) + 8 weight matrices (64K each)
__global__ __launch_bounds__(256) void cast_kernel(CastArgs ca, _Float16* __restrict__ dst) {
    size_t i4 = ((size_t)blockIdx.x * 256 + threadIdx.x) * 4;
    const float* s; size_t off;
    if (i4 < TBL_SZ)            { s = ca.src[0]; off = i4; }
    else if (i4 < 2 * TBL_SZ)   { s = ca.src[1]; off = i4 - TBL_SZ; }
    else { size_t r = i4 - 2 * TBL_SZ; s = ca.src[2 + (r >> 16)]; off = r & 65535; }
    float4 v = *(const float4*)(s + off);
    half4 h = {(_Float16)v.x, (_Float16)v.y, (_Float16)v.z, (_Float16)v.w};
    *(half4*)(dst + i4) = h;
}

// C[m,n] = A[m,:] . W[n,:] + b[n] via MFMA f16, 8 jobs (blockIdx.z)
__global__ __launch_bounds__(256) void gemm_mfma(const _Float16* __restrict__ Ah,
        const _Float16* __restrict__ Wh, BiasArgs ba, _Float16* __restrict__ tblBase) {
    int j = blockIdx.z;
    const _Float16* A = Ah + (size_t)(j >> 2) * TBL_SZ;
    const _Float16* W = Wh + (size_t)j * 65536;
    const float* bias = ba.b[j];
    _Float16* out = tblBase + (size_t)j * TBL_SZ;
    int wave = threadIdx.x >> 6, lane = threadIdx.x & 63;
    int quad = lane >> 4, l16 = lane & 15;
    int mr = blockIdx.x * 64 + (wave >> 1) * 32;
    int nc = blockIdx.y * 64 + (wave & 1) * 32;
    const _Float16* a0p = A + (size_t)(mr + l16) * 256 + quad * 8;
    const _Float16* a1p = a0p + 16 * 256;
    const _Float16* b0p = W + (size_t)(nc + l16) * 256 + quad * 8;
    const _Float16* b1p = b0p + 16 * 256;
    floatx4 acc00 = {0,0,0,0}, acc01 = {0,0,0,0}, acc10 = {0,0,0,0}, acc11 = {0,0,0,0};
#pragma unroll
    for (int k0 = 0; k0 < 256; k0 += 32) {
        half8 a0 = *(const half8*)(a0p + k0);
        half8 a1 = *(const half8*)(a1p + k0);
        half8 b0 = *(const half8*)(b0p + k0);
        half8 b1 = *(const half8*)(b1p + k0);
        acc00 = __builtin_amdgcn_mfma_f32_16x16x32_f16(a0, b0, acc00, 0, 0, 0);
        acc01 = __builtin_amdgcn_mfma_f32_16x16x32_f16(a0, b1, acc01, 0, 0, 0);
        acc10 = __builtin_amdgcn_mfma_f32_16x16x32_f16(a1, b0, acc10, 0, 0, 0);
        acc11 = __builtin_amdgcn_mfma_f32_16x16x32_f16(a1, b1, acc11, 0, 0, 0);
    }
    float bc0 = bias[nc + l16];
    float bc1 = bias[nc + 16 + l16];
#pragma unroll
    for (int i = 0; i < 4; ++i) {
        int r0 = mr + quad * 4 + i;
        out[(size_t)r0 * 256 + nc + l16]             = (_Float16)(acc00[i] + bc0);
        out[(size_t)r0 * 256 + nc + 16 + l16]        = (_Float16)(acc01[i] + bc1);
        out[(size_t)(r0 + 16) * 256 + nc + l16]      = (_Float16)(acc10[i] + bc0);
        out[(size_t)(r0 + 16) * 256 + nc + 16 + l16] = (_Float16)(acc11[i] + bc1);
    }
}

// Whin (1x256) + per-head dst scores: one wave per output row, 64 blocks
__global__ __launch_bounds__(256) void whin_kernel(const float* __restrict__ fs,
        const float* __restrict__ Win, const float* __restrict__ bin,
        const float* __restrict__ attP, const float* __restrict__ attA,
        float* __restrict__ whin, float* __restrict__ scd) {
    int wave = threadIdx.x >> 6, lane = threadIdx.x & 63;
    int o = blockIdx.x * 4 + wave;
    float4 w = *(const float4*)&Win[(size_t)o * 256 + lane * 4];
    float4 f = *(const float4*)&fs[lane * 4];
    float v = w.x * f.x + w.y * f.y + w.z * f.z + w.w * f.w;
    for (int d = 32; d; d >>= 1) v += __shfl_xor(v, d);
    if (lane == 0) {
        v += bin[o];
        whin[o] = v;
        atomicAdd(&scd[o >> 6], v * attP[o]);
        atomicAdd(&scd[4 + (o >> 6)], v * attA[o]);
    }
}

// 10 score tables [4096,4] from f16 Wh tables
__global__ __launch_bounds__(256) void score_kernel(const _Float16* __restrict__ tblBase,
                                                    ScoreArgs sa, float* __restrict__ scoreBase) {
    int job = blockIdx.y;
    int wave = threadIdx.x >> 6, lane = threadIdx.x & 63;
    int node = blockIdx.x * 4 + wave;
    const _Float16* wh = tblBase + (size_t)sa.tbl[job] * TBL_SZ + (size_t)node * 256 + lane * 4;
    half4 w = *(const half4*)wh;
    float4 a = *(const float4*)&sa.att[job][lane * 4];
    float p = (float)w[0] * a.x + (float)w[1] * a.y + (float)w[2] * a.z + (float)w[3] * a.w;
    p += __shfl_xor(p, 1); p += __shfl_xor(p, 2); p += __shfl_xor(p, 4); p += __shfl_xor(p, 8);
    if ((lane & 15) == 0)
        scoreBase[(size_t)job * NPA * 4 + (size_t)node * 4 + (lane >> 4)] = p;
}

__global__ __launch_bounds__(256) void count_kernel(EdgeArgs ea, int* __restrict__ counts) {
    int idx = blockIdx.x * 256 + threadIdx.x;
    int r = idx >> 17;
    int e = idx & (EDG - 1);
    atomicAdd(&counts[r * NPA + ea.dst[r][e]], 1);
}

__global__ __launch_bounds__(1024) void scan_kernel(const int* __restrict__ counts,
                                                    int* __restrict__ offs, int* __restrict__ cur) {
    int r = blockIdx.x;
    int t = threadIdx.x;
    const int* c = counts + (size_t)r * NPA;
    int4 v = *(const int4*)&c[t * 4];
    int lsum = v.x + v.y + v.z + v.w;
    __shared__ int s[1024];
    s[t] = lsum;
    __syncthreads();
    for (int d = 1; d < 1024; d <<= 1) {
        int add = (t >= d) ? s[t - d] : 0;
        __syncthreads();
        s[t] += add;
        __syncthreads();
    }
    int base = s[t] - lsum;
    int4 ov = {base, base + v.x, base + v.x + v.y, base + v.x + v.y + v.z};
    *(int4*)&offs[(size_t)r * OS + t * 4] = ov;
    *(int4*)&cur[(size_t)r * NPA + t * 4] = ov;
    if (t == 1023) offs[(size_t)r * OS + NPA] = s[1023];
}

// per-edge head-softmax attn, packed {src, a01, a23, 0}, written dst-sorted (1 store)
__global__ __launch_bounds__(256) void scatter_attn(EdgeArgs ea, const float* __restrict__ scoreBase,
        int* __restrict__ cur, int4* __restrict__ pkt) {
    int idx = blockIdx.x * 256 + threadIdx.x;
    int r = idx >> 17;
    int e = idx & (EDG - 1);
    int s = ea.src[r][e];
    int d = ea.dst[r][e];
    const float* as = scoreBase + (size_t)r * NPA * 4;
    const float* ad = scoreBase + (size_t)(4 + r) * NPA * 4;
    float4 av = *(const float4*)&as[(size_t)s * 4];
    float4 dv = *(const float4*)&ad[(size_t)d * 4];
    float x0 = lrelu(av.x + dv.x), x1 = lrelu(av.y + dv.y);
    float x2 = lrelu(av.z + dv.z), x3 = lrelu(av.w + dv.w);
    float m = fmaxf(fmaxf(x0, x1), fmaxf(x2, x3));
    float e0 = __expf(x0 - m), e1 = __expf(x1 - m), e2 = __expf(x2 - m), e3 = __expf(x3 - m);
    float inv = 1.0f / (e0 + e1 + e2 + e3);
    int pos = atomicAdd(&cur[r * NPA + d], 1);
    int4 pk = {s, pack2(e0 * inv, e1 * inv), pack2(e2 * inv, e3 * inv), 0};
    pkt[(size_t)r * EDG + pos] = pk;
}

// per dst node: out = relu(Wh_skip + sum over 2 relations of attn*Wh_src)
// wave split into 2 halves: each half processes a different edge (half8 row slice per lane),
// unrolled 2x per half (4 edges in flight), packet loads software-pipelined.
__global__ __launch_bounds__(256) void agg_kernel(const int* __restrict__ offs,
        const int4* __restrict__ pkt, const _Float16* __restrict__ tblBase,
        float* __restrict__ outBase) {
    int side = blockIdx.y;                      // 0 = P, 1 = A
    int wave = threadIdx.x >> 6, lane = threadIdx.x & 63;
    int dn = blockIdx.x * 4 + wave;
    int h = lane >> 5, l32 = lane & 31;
    int head = l32 >> 3;
    float acc[8] = {0, 0, 0, 0, 0, 0, 0, 0};
    const int srcIdx[4] = {1, 2, 5, 6};
    const int4 z = {0, 0, 0, 0};
#pragma unroll
    for (int q = 0; q < 2; ++q) {
        int r = side + q * 2;
        const int* of = offs + (size_t)r * OS;
        const int4* pkb = pkt + (size_t)r * EDG;
        const _Float16* wh = tblBase + (size_t)srcIdx[r] * TBL_SZ;
        int beg = of[dn], end = of[dn + 1];
        int i = beg;
        int4 p0 = (i + h < end) ? pkb[i + h] : z;
        int4 p1 = (i + 2 + h < end) ? pkb[i + 2 + h] : z;
        while (i < end) {
            int ni = i + 4;
            half8 w0 = *(const half8*)(wh + (size_t)p0.x * 256 + l32 * 8);
            half8 w1 = *(const half8*)(wh + (size_t)p1.x * 256 + l32 * 8);
            int4 n0 = (ni + h < end) ? pkb[ni + h] : z;
            int4 n1 = (ni + 2 + h < end) ? pkb[ni + 2 + h] : z;
            float a0 = asel(p0, head);
            float a1 = asel(p1, head);
#pragma unroll
            for (int k = 0; k < 8; ++k)
                acc[k] += a0 * (float)w0[k] + a1 * (float)w1[k];
            p0 = n0; p1 = n1; i = ni;
        }
    }
#pragma unroll
    for (int k = 0; k < 8; ++k) acc[k] += __shfl_xor(acc[k], 32);
    if (h == 0) {
        const _Float16* skip = tblBase + (size_t)(side * 4) * TBL_SZ + (size_t)dn * 256 + l32 * 8;
        half8 sv = *(const half8*)skip;
        float* op = outBase + ((size_t)side * NPA + dn) * 256 + l32 * 8;
        float4 o0 = {fmaxf(acc[0] + (float)sv[0], 0.f), fmaxf(acc[1] + (float)sv[1], 0.f),
                     fmaxf(acc[2] + (float)sv[2], 0.f), fmaxf(acc[3] + (float)sv[3], 0.f)};
        float4 o1 = {fmaxf(acc[4] + (float)sv[4], 0.f), fmaxf(acc[5] + (float)sv[5], 0.f),
                     fmaxf(acc[6] + (float)sv[6], 0.f), fmaxf(acc[7] + (float)sv[7], 0.f)};
        *(float4*)op = o0;
        *(float4*)(op + 4) = o1;
    }
}

// state relations p2s (tbl3) / a2s (tbl7): softmax over 4096 nodes
__global__ __launch_bounds__(256) void state_kernel(const _Float16* __restrict__ tblBase,
        const float* __restrict__ scoreBase, const float* __restrict__ scd,
        float* __restrict__ den, float* __restrict__ num) {
    int r = blockIdx.y;
    int blk = blockIdx.x;                       // 0..127
    int t = threadIdx.x;
    int h = t >> 6;
    const _Float16* wh = tblBase + (size_t)(r == 0 ? 3 : 7) * TBL_SZ;
    const float* as = scoreBase + (size_t)(8 + r) * NPA * 4;
    float dh = scd[r * 4 + h];
    float dsum = 0.0f, acc = 0.0f;
    for (int i = blk; i < NPA; i += 128) {
        float x = lrelu(as[(size_t)i * 4 + h] + dh);
        float w = __expf(x);
        dsum += w;
        acc += w * (float)wh[(size_t)i * 256 + t];
    }
    atomicAdd(&num[r * 256 + t], acc);
    if ((t & 63) == 0) atomicAdd(&den[r * 4 + h], dsum);
}

__global__ __launch_bounds__(256) void state_final(const float* __restrict__ whin,
        const float* __restrict__ den, const float* __restrict__ num, float* __restrict__ out) {
    int t = threadIdx.x;
    int h = t >> 6;
    float v = whin[t] + num[t] / den[h] + num[256 + t] / den[4 + h];
    out[t] = v > 0.0f ? v : 0.0f;
}

extern "C" void kernel_launch(void* const* d_in, const int* in_sizes, int n_in,
                              void* d_out, int out_size, void* d_ws, size_t ws_size,
                              hipStream_t stream) {
    auto F = [&](int i) { return (const float*)d_in[i]; };
    char* ws = (char*)d_ws;
    _Float16* Ah  = (_Float16*)(ws + B_AH);
    _Float16* Wh  = (_Float16*)(ws + B_WH);
    _Float16* tbl = (_Float16*)(ws + B_TBL);
    float* score  = (float*)(ws + B_SCORE);
    int* cnt      = (int*)(ws + B_CNT);
    int* offs     = (int*)(ws + B_OFFS);
    int* cur      = (int*)(ws + B_CUR);
    int4* pkt     = (int4*)(ws + B_PKT);
    float* whin   = (float*)(ws + B_WHIN);
    float* scd    = (float*)(ws + B_SCD);
    float* den    = (float*)(ws + B_DEN);
    float* num    = (float*)(ws + B_NUM);

    hipMemsetAsync(cnt, 0, 4 * NPA * sizeof(int), stream);
    hipMemsetAsync(scd, 0, (8 + 8 + 512) * sizeof(float), stream);

    CastArgs ca = {{F(0), F(1), F(3), F(7), F(9), F(15), F(5), F(11), F(13), F(17)}};
    cast_kernel<<<2560, 256, 0, stream>>>(ca, Ah);

    BiasArgs ba = {{F(4), F(8), F(10), F(16), F(6), F(12), F(14), F(18)}};
    gemm_mfma<<<dim3(64, 4, 8), 256, 0, stream>>>(Ah, Wh, ba, tbl);

    whin_kernel<<<64, 256, 0, stream>>>(F(2), F(19), F(20), F(30), F(32), whin, scd);

    ScoreArgs sa = {{F(21), F(23), F(25), F(27), F(22), F(24), F(26), F(28), F(29), F(31)},
                    {1, 2, 5, 6, 0, 4, 0, 4, 3, 7}};
    score_kernel<<<dim3(1024, 10), 256, 0, stream>>>(tbl, sa, score);

    EdgeArgs ea = {{(const int*)d_in[33], (const int*)d_in[35], (const int*)d_in[37], (const int*)d_in[39]},
                   {(const int*)d_in[34], (const int*)d_in[36], (const int*)d_in[38], (const int*)d_in[40]}};
    count_kernel<<<2048, 256, 0, stream>>>(ea, cnt);
    scan_kernel<<<4, 1024, 0, stream>>>(cnt, offs, cur);
    scatter_attn<<<2048, 256, 0, stream>>>(ea, score, cur, pkt);

    agg_kernel<<<dim3(1024, 2), 256, 0, stream>>>(offs, pkt, tbl, (float*)d_out);

    state_kernel<<<dim3(128, 2), 256, 0, stream>>>(tbl, score, scd, den, num);
    state_final<<<1, 256, 0, stream>>>(whin, den, num, (float*)d_out + 2 * TBL_SZ);
}